// Round 1
// baseline (309.764 us; speedup 1.0000x reference)
//
#include <hip/hip_runtime.h>
#include <math.h>

// PPO loss with GAE.  B=4096 rows, T=2048 steps, fp32 everywhere.
// Inputs (setup_inputs order): 0 rewards(B,T) 1 values(B,T+1) 2 ref_probs(unused)
//                              3 old_probs(B,T) 4 curr_probs(B,T) 5 masks(B,T)
// Output: 4 floats: total, ppo, 0.5*value_loss, 0.01*entropy_loss
//
// Plan:
//  K1  gae_kernel      : per-row parallel affine scan -> raw advantages to ws,
//                        accumulate sum(adv), sum(adv^2)  [sum^2 also = value loss]
//  K2  finalize_stats  : 1 thread -> mean, 1/(std+eps)
//  K3  ppo_kernel      : stream adv/old/curr, accumulate sum(min(surr1,surr2)),
//                        sum(c*log(c+eps))
//  K4  finalize_out    : 1 thread -> 4 output scalars

#define GAMMA     0.99f
#define LAM       0.95f
#define CLIP_LO   0.8f
#define CLIP_HI   1.2f
#define EPSF      1e-9f

constexpr int    BB = 4096;
constexpr int    TT = 2048;
constexpr long long NN = (long long)BB * TT;   // 8388608

// ws layout: [0,32)  4 doubles: sum_adv, sum_adv2, sum_min, sum_ent
//            [32,40) 2 floats : mean, inv_std_eps
//            [64, 64+B*T*4) raw advantages
static constexpr size_t ADV_OFF = 64;

// ---------------------------------------------------------------- K1: GAE scan
__global__ __launch_bounds__(256) void gae_kernel(
    const float* __restrict__ rewards,
    const float* __restrict__ values,
    const float* __restrict__ masks,
    float* __restrict__ adv_out,
    double* __restrict__ accum)
{
    const int row = blockIdx.x;
    const int tid = threadIdx.x;
    const int t0  = tid * 8;

    const float* rrow = rewards + (size_t)row * TT;
    const float* mrow = masks   + (size_t)row * TT;
    const float* vrow = values  + (size_t)row * (TT + 1);

    // rewards/masks rows are 16B-aligned (T=2048); values rows (stride 2049) are not -> scalar loads
    float4 r0 = *(const float4*)(rrow + t0);
    float4 r1 = *(const float4*)(rrow + t0 + 4);
    float4 m0 = *(const float4*)(mrow + t0);
    float4 m1 = *(const float4*)(mrow + t0 + 4);
    float r[8] = {r0.x, r0.y, r0.z, r0.w, r1.x, r1.y, r1.z, r1.w};
    float m[8] = {m0.x, m0.y, m0.z, m0.w, m1.x, m1.y, m1.z, m1.w};
    float v[9];
#pragma unroll
    for (int j = 0; j < 9; ++j) v[j] = vrow[t0 + j];

    // delta[t] = r + gamma*v_next*m - v ;  c[t] = gamma*lam*m[t]
    float delta[8], c[8];
#pragma unroll
    for (int j = 0; j < 8; ++j) {
        delta[j] = r[j] + GAMMA * v[j + 1] * m[j] - v[j];
        c[j]     = (GAMMA * LAM) * m[j];
    }

    // chunk-local reverse scan with zero carry; suffix products S[j] = c[j]*...*c[7]
    float la[8], S[8];
    la[7] = delta[7];
    S[7]  = c[7];
#pragma unroll
    for (int j = 6; j >= 0; --j) {
        la[j] = delta[j] + c[j] * la[j + 1];
        S[j]  = c[j] * S[j + 1];
    }

    // block-level reverse inclusive scan of affine fns f_i(x) = la0_i + P_i * x
    __shared__ float sA[2][256];
    __shared__ float sB[2][256];
    int buf = 0;
    sA[0][tid] = S[0];
    sB[0][tid] = la[0];
    __syncthreads();
#pragma unroll
    for (int d = 1; d < 256; d <<= 1) {
        float A = sA[buf][tid], Bv = sB[buf][tid];
        if (tid + d < 256) {
            float A2 = sA[buf][tid + d], B2 = sB[buf][tid + d];
            Bv = Bv + A * B2;   // f_[tid..] = f_[tid..tid+d-1] o f_[tid+d..]
            A  = A * A2;
        }
        buf ^= 1;
        sA[buf][tid] = A;
        sB[buf][tid] = Bv;
        __syncthreads();
    }
    // carry into chunk tid = adv at t0+8 = scan result of chunk tid+1 applied to 0
    float carry = (tid < 255) ? sB[buf][tid + 1] : 0.0f;

    float a[8], s1 = 0.f, s2 = 0.f;
#pragma unroll
    for (int j = 0; j < 8; ++j) {
        a[j] = la[j] + S[j] * carry;
        s1 += a[j];
        s2 += a[j] * a[j];
    }
    float4 o0 = {a[0], a[1], a[2], a[3]};
    float4 o1 = {a[4], a[5], a[6], a[7]};
    *(float4*)(adv_out + (size_t)row * TT + t0)     = o0;
    *(float4*)(adv_out + (size_t)row * TT + t0 + 4) = o1;

    // block reduce s1, s2 -> double atomics
#pragma unroll
    for (int off = 32; off > 0; off >>= 1) {
        s1 += __shfl_down(s1, off, 64);
        s2 += __shfl_down(s2, off, 64);
    }
    __shared__ float w1[4], w2[4];
    const int wave = tid >> 6, lane = tid & 63;
    if (lane == 0) { w1[wave] = s1; w2[wave] = s2; }
    __syncthreads();
    if (tid == 0) {
        float t1 = w1[0] + w1[1] + w1[2] + w1[3];
        float t2 = w2[0] + w2[1] + w2[2] + w2[3];
        atomicAdd(&accum[0], (double)t1);
        atomicAdd(&accum[1], (double)t2);
    }
}

// ------------------------------------------------------- K2: mean / inv(std+eps)
__global__ void finalize_stats(const double* __restrict__ accum,
                               float* __restrict__ stats)
{
    double s1 = accum[0], s2 = accum[1];
    double mean = s1 / (double)NN;
    double var  = (s2 - s1 * s1 / (double)NN) / (double)(NN - 1);  // ddof=1
    double sd   = sqrt(var);
    stats[0] = (float)mean;
    stats[1] = (float)(1.0 / (sd + 1e-9));
}

// ------------------------------------------------- K3: ppo surrogate + entropy
__global__ __launch_bounds__(256) void ppo_kernel(
    const float* __restrict__ adv,
    const float* __restrict__ oldp,
    const float* __restrict__ currp,
    const float* __restrict__ stats,
    double* __restrict__ accum)
{
    const float mean = stats[0];
    const float inv  = stats[1];
    const long long n4 = NN / 4;

    const float4* a4 = (const float4*)adv;
    const float4* o4 = (const float4*)oldp;
    const float4* c4 = (const float4*)currp;

    float sm = 0.f, se = 0.f;
    long long idx    = (long long)blockIdx.x * blockDim.x + threadIdx.x;
    long long stride = (long long)gridDim.x * blockDim.x;
    for (long long i = idx; i < n4; i += stride) {
        float4 a = a4[i], o = o4[i], c = c4[i];
        float av[4] = {a.x, a.y, a.z, a.w};
        float ov[4] = {o.x, o.y, o.z, o.w};
        float cv[4] = {c.x, c.y, c.z, c.w};
#pragma unroll
        for (int j = 0; j < 4; ++j) {
            float an    = (av[j] - mean) * inv;
            float ratio = cv[j] / (ov[j] + EPSF);
            float rc    = fminf(fmaxf(ratio, CLIP_LO), CLIP_HI);
            sm += fminf(ratio * an, rc * an);
            se += cv[j] * __logf(cv[j] + EPSF);
        }
    }

#pragma unroll
    for (int off = 32; off > 0; off >>= 1) {
        sm += __shfl_down(sm, off, 64);
        se += __shfl_down(se, off, 64);
    }
    __shared__ float w1[4], w2[4];
    const int wave = threadIdx.x >> 6, lane = threadIdx.x & 63;
    if (lane == 0) { w1[wave] = sm; w2[wave] = se; }
    __syncthreads();
    if (threadIdx.x == 0) {
        float t1 = w1[0] + w1[1] + w1[2] + w1[3];
        float t2 = w2[0] + w2[1] + w2[2] + w2[3];
        atomicAdd(&accum[2], (double)t1);
        atomicAdd(&accum[3], (double)t2);
    }
}

// ------------------------------------------------------------- K4: final output
__global__ void finalize_out(const double* __restrict__ accum,
                             float* __restrict__ out)
{
    double invN = 1.0 / (double)NN;
    double vl   = 0.5  * (accum[1] * invN);          // 0.5 * mean(raw_adv^2)
    double ppo  = -(accum[2] * invN);
    double ent  = -0.01 * (accum[3] * invN);
    out[0] = (float)(ppo + vl + ent);
    out[1] = (float)ppo;
    out[2] = (float)vl;
    out[3] = (float)ent;
}

extern "C" void kernel_launch(void* const* d_in, const int* in_sizes, int n_in,
                              void* d_out, int out_size, void* d_ws, size_t ws_size,
                              hipStream_t stream) {
    const float* rewards = (const float*)d_in[0];
    const float* values  = (const float*)d_in[1];
    // d_in[2] = ref_probs: unused by the reference -> never touched
    const float* oldp    = (const float*)d_in[3];
    const float* currp   = (const float*)d_in[4];
    const float* masks   = (const float*)d_in[5];

    double* accum = (double*)d_ws;
    float*  stats = (float*)((char*)d_ws + 32);
    float*  advws = (float*)((char*)d_ws + ADV_OFF);
    float*  out   = (float*)d_out;

    hipMemsetAsync(d_ws, 0, 64, stream);   // zero accumulators + stats

    gae_kernel<<<BB, 256, 0, stream>>>(rewards, values, masks, advws, accum);
    finalize_stats<<<1, 1, 0, stream>>>(accum, stats);
    ppo_kernel<<<2048, 256, 0, stream>>>(advws, oldp, currp, stats, accum);
    finalize_out<<<1, 1, 0, stream>>>(accum, out);
}

// Round 2
// 209.607 us; speedup vs baseline: 1.4778x; 1.4778x over previous
//
#include <hip/hip_runtime.h>
#include <math.h>

// PPO loss with GAE.  B=4096 rows, T=2048 steps, fp32 everywhere.
// Inputs: 0 rewards(B,T) 1 values(B,T+1) 2 ref_probs(UNUSED) 3 old_probs(B,T)
//         4 curr_probs(B,T) 5 masks(B,T)
// Output: 4 floats: total, ppo, 0.5*value_loss, 0.01*entropy_loss
//
// R2 change: same-address double atomics (8192 in gae, 4096 in ppo) were
// serializing at one L2 slice (~100 us in gae alone). Replaced with per-block
// float2 partials in ws + deterministic double tree-reduce in the finalize
// kernels. memset dropped (nothing needs zero-init).

#define GAMMA     0.99f
#define LAM       0.95f
#define CLIP_LO   0.8f
#define CLIP_HI   1.2f
#define EPSF      1e-9f

constexpr int BB = 4096;
constexpr int TT = 2048;
constexpr long long NN = (long long)BB * TT;   // 8388608
constexpr int PPO_BLOCKS = 2048;

// ws layout:
//  [0,32)                 stats: float mean, float inv_std_eps, double sum_adv2
//  [64, 64+32K)           gae partials: 4096 x float2 (sum_adv, sum_adv2)
//  [64+32K, 64+48K)       ppo partials: 2048 x float2 (sum_min, sum_ent)
//  [49216, 49216+32M)     raw advantages (16B aligned)
struct Stats { float mean; float inv; double sum2; };
static constexpr size_t GAE_PART_OFF = 64;
static constexpr size_t PPO_PART_OFF = 64 + 4096 * sizeof(float2);
static constexpr size_t ADV_OFF      = PPO_PART_OFF + 2048 * sizeof(float2); // 49216

// ---------------------------------------------------------------- K1: GAE scan
__global__ __launch_bounds__(256) void gae_kernel(
    const float* __restrict__ rewards,
    const float* __restrict__ values,
    const float* __restrict__ masks,
    float* __restrict__ adv_out,
    float2* __restrict__ partials)
{
    const int row = blockIdx.x;
    const int tid = threadIdx.x;
    const int t0  = tid * 8;

    const float* rrow = rewards + (size_t)row * TT;
    const float* mrow = masks   + (size_t)row * TT;
    const float* vrow = values  + (size_t)row * (TT + 1);

    float4 r0 = *(const float4*)(rrow + t0);
    float4 r1 = *(const float4*)(rrow + t0 + 4);
    float4 m0 = *(const float4*)(mrow + t0);
    float4 m1 = *(const float4*)(mrow + t0 + 4);
    float r[8] = {r0.x, r0.y, r0.z, r0.w, r1.x, r1.y, r1.z, r1.w};
    float m[8] = {m0.x, m0.y, m0.z, m0.w, m1.x, m1.y, m1.z, m1.w};
    float v[9];
#pragma unroll
    for (int j = 0; j < 9; ++j) v[j] = vrow[t0 + j];

    // delta[t] = r + gamma*v_next*m - v ;  c[t] = gamma*lam*m[t]
    float delta[8], c[8];
#pragma unroll
    for (int j = 0; j < 8; ++j) {
        delta[j] = r[j] + GAMMA * v[j + 1] * m[j] - v[j];
        c[j]     = (GAMMA * LAM) * m[j];
    }

    // chunk-local reverse scan with zero carry; suffix products S[j]
    float la[8], S[8];
    la[7] = delta[7];
    S[7]  = c[7];
#pragma unroll
    for (int j = 6; j >= 0; --j) {
        la[j] = delta[j] + c[j] * la[j + 1];
        S[j]  = c[j] * S[j + 1];
    }

    // block-level reverse inclusive scan of affine fns f_i(x) = la0_i + P_i*x
    __shared__ float sA[2][256];
    __shared__ float sB[2][256];
    int buf = 0;
    sA[0][tid] = S[0];
    sB[0][tid] = la[0];
    __syncthreads();
#pragma unroll
    for (int d = 1; d < 256; d <<= 1) {
        float A = sA[buf][tid], Bv = sB[buf][tid];
        if (tid + d < 256) {
            float A2 = sA[buf][tid + d], B2 = sB[buf][tid + d];
            Bv = Bv + A * B2;
            A  = A * A2;
        }
        buf ^= 1;
        sA[buf][tid] = A;
        sB[buf][tid] = Bv;
        __syncthreads();
    }
    float carry = (tid < 255) ? sB[buf][tid + 1] : 0.0f;

    float a[8], s1 = 0.f, s2 = 0.f;
#pragma unroll
    for (int j = 0; j < 8; ++j) {
        a[j] = la[j] + S[j] * carry;
        s1 += a[j];
        s2 += a[j] * a[j];
    }
    float4 o0 = {a[0], a[1], a[2], a[3]};
    float4 o1 = {a[4], a[5], a[6], a[7]};
    *(float4*)(adv_out + (size_t)row * TT + t0)     = o0;
    *(float4*)(adv_out + (size_t)row * TT + t0 + 4) = o1;

    // block reduce s1,s2 -> one float2 store per block (NO global atomics)
#pragma unroll
    for (int off = 32; off > 0; off >>= 1) {
        s1 += __shfl_down(s1, off, 64);
        s2 += __shfl_down(s2, off, 64);
    }
    __shared__ float w1[4], w2[4];
    const int wave = tid >> 6, lane = tid & 63;
    if (lane == 0) { w1[wave] = s1; w2[wave] = s2; }
    __syncthreads();
    if (tid == 0) {
        float2 p = {w1[0] + w1[1] + w1[2] + w1[3],
                    w2[0] + w2[1] + w2[2] + w2[3]};
        partials[row] = p;
    }
}

// ------------------------------------- K2: reduce gae partials -> mean, inv_std
__global__ __launch_bounds__(256) void finalize_stats(
    const float2* __restrict__ gp, Stats* __restrict__ stats)
{
    const int tid = threadIdx.x;
    __shared__ double l1[256], l2[256];
    double s1 = 0.0, s2 = 0.0;
    for (int i = tid; i < BB; i += 256) {
        float2 p = gp[i];
        s1 += (double)p.x;
        s2 += (double)p.y;
    }
    l1[tid] = s1; l2[tid] = s2;
    __syncthreads();
    for (int st = 128; st > 0; st >>= 1) {
        if (tid < st) { l1[tid] += l1[tid + st]; l2[tid] += l2[tid + st]; }
        __syncthreads();
    }
    if (tid == 0) {
        double S1 = l1[0], S2 = l2[0];
        double mean = S1 / (double)NN;
        double var  = (S2 - S1 * S1 / (double)NN) / (double)(NN - 1); // ddof=1
        stats->mean = (float)mean;
        stats->inv  = (float)(1.0 / (sqrt(var) + 1e-9));
        stats->sum2 = S2;
    }
}

// ------------------------------------------------- K3: ppo surrogate + entropy
__global__ __launch_bounds__(256) void ppo_kernel(
    const float* __restrict__ adv,
    const float* __restrict__ oldp,
    const float* __restrict__ currp,
    const Stats* __restrict__ stats,
    float2* __restrict__ partials)
{
    const float mean = stats->mean;
    const float inv  = stats->inv;
    const long long n4 = NN / 4;

    const float4* a4 = (const float4*)adv;
    const float4* o4 = (const float4*)oldp;
    const float4* c4 = (const float4*)currp;

    float sm = 0.f, se = 0.f;
    long long idx    = (long long)blockIdx.x * blockDim.x + threadIdx.x;
    long long stride = (long long)gridDim.x * blockDim.x;
    for (long long i = idx; i < n4; i += stride) {
        float4 a = a4[i], o = o4[i], c = c4[i];
        float av[4] = {a.x, a.y, a.z, a.w};
        float ov[4] = {o.x, o.y, o.z, o.w};
        float cv[4] = {c.x, c.y, c.z, c.w};
#pragma unroll
        for (int j = 0; j < 4; ++j) {
            float an    = (av[j] - mean) * inv;
            float ratio = cv[j] / (ov[j] + EPSF);
            float rc    = fminf(fmaxf(ratio, CLIP_LO), CLIP_HI);
            sm += fminf(ratio * an, rc * an);
            se += cv[j] * __logf(cv[j] + EPSF);
        }
    }

#pragma unroll
    for (int off = 32; off > 0; off >>= 1) {
        sm += __shfl_down(sm, off, 64);
        se += __shfl_down(se, off, 64);
    }
    __shared__ float w1[4], w2[4];
    const int wave = threadIdx.x >> 6, lane = threadIdx.x & 63;
    if (lane == 0) { w1[wave] = sm; w2[wave] = se; }
    __syncthreads();
    if (threadIdx.x == 0) {
        float2 p = {w1[0] + w1[1] + w1[2] + w1[3],
                    w2[0] + w2[1] + w2[2] + w2[3]};
        partials[blockIdx.x] = p;
    }
}

// --------------------------------- K4: reduce ppo partials -> 4 output scalars
__global__ __launch_bounds__(256) void finalize_out(
    const float2* __restrict__ pp,
    const Stats* __restrict__ stats,
    float* __restrict__ out)
{
    const int tid = threadIdx.x;
    __shared__ double l1[256], l2[256];
    double s1 = 0.0, s2 = 0.0;
    for (int i = tid; i < PPO_BLOCKS; i += 256) {
        float2 p = pp[i];
        s1 += (double)p.x;
        s2 += (double)p.y;
    }
    l1[tid] = s1; l2[tid] = s2;
    __syncthreads();
    for (int st = 128; st > 0; st >>= 1) {
        if (tid < st) { l1[tid] += l1[tid + st]; l2[tid] += l2[tid + st]; }
        __syncthreads();
    }
    if (tid == 0) {
        double invN = 1.0 / (double)NN;
        double vl   = 0.5  * (stats->sum2 * invN);   // 0.5 * mean(raw_adv^2)
        double ppo  = -(l1[0] * invN);
        double ent  = -0.01 * (l2[0] * invN);
        out[0] = (float)(ppo + vl + ent);
        out[1] = (float)ppo;
        out[2] = (float)vl;
        out[3] = (float)ent;
    }
}

extern "C" void kernel_launch(void* const* d_in, const int* in_sizes, int n_in,
                              void* d_out, int out_size, void* d_ws, size_t ws_size,
                              hipStream_t stream) {
    const float* rewards = (const float*)d_in[0];
    const float* values  = (const float*)d_in[1];
    // d_in[2] = ref_probs: unused by the reference
    const float* oldp    = (const float*)d_in[3];
    const float* currp   = (const float*)d_in[4];
    const float* masks   = (const float*)d_in[5];

    Stats*  stats = (Stats*)d_ws;
    float2* gaep  = (float2*)((char*)d_ws + GAE_PART_OFF);
    float2* ppop  = (float2*)((char*)d_ws + PPO_PART_OFF);
    float*  advws = (float*)((char*)d_ws + ADV_OFF);
    float*  out   = (float*)d_out;

    gae_kernel<<<BB, 256, 0, stream>>>(rewards, values, masks, advws, gaep);
    finalize_stats<<<1, 256, 0, stream>>>(gaep, stats);
    ppo_kernel<<<PPO_BLOCKS, 256, 0, stream>>>(advws, oldp, currp, stats, ppop);
    finalize_out<<<1, 256, 0, stream>>>(ppop, stats, out);
}